// Round 8
// baseline (94.429 us; speedup 1.0000x reference)
//
#include <hip/hip_runtime.h>
#include <math.h>

#define B_TOTAL 2048
#define I_TOTAL 2048
#define O_TOTAL 2048
#define KW 64
#define NIN 6
#define BLOCK 256
#define TILE_B 16              // b-rows per block
#define CH 2                   // rows per LDS buffer (double-buffered)
#define NCHUNK (TILE_B / CH)   // 8
#define OGROUP (BLOCK / 2)     // 128 o's per block (lane-pair k-split)
#define BBLOCKS (B_TOTAL / TILE_B)   /* 128 */
#define OBLOCKS (O_TOTAL / OGROUP)   /* 16  */

// ---------------------------------------------------------------------------
// prep_kernel: v2's transpose structure, NEW half-split diff layout.
//  wT[k][o], k = 32h + j (h = k-half owned by lane h of a pair):
//    j in [0,16):  sigmoid(table[o][32h+j])                        ("lo")
//    j in [16,32): sigmoid(table[o][32h+j]) - sigmoid(table[o][32h+j-16])
//  i.e. the precomputed diff is now across BIT 4 within each half (bit 5 is
//  combined across the lane pair in main). Mapping -> m32T[i][o] as before.
// ---------------------------------------------------------------------------
__global__ __launch_bounds__(BLOCK) void prep_kernel(
    const float* __restrict__ table,
    const unsigned int* __restrict__ map_raw,
    float* __restrict__ wT,
    int* __restrict__ m32T)
{
    const int t = threadIdx.x;

    if (blockIdx.x < 32) {
        __shared__ float sm[64][65];          // +1 pad: conflict-free col reads
        const int o0 = blockIdx.x * 64;
        #pragma unroll
        for (int rep = 0; rep < 16; ++rep) {
            int idx = rep * 256 + t;          // 0..4095
            int ol = idx >> 6, k = idx & 63;
            float v = table[(o0 + ol) * KW + k];      // coalesced read
            sm[ol][k] = 1.0f / (1.0f + __expf(-v));
        }
        __syncthreads();
        #pragma unroll
        for (int rep = 0; rep < 16; ++rep) {
            int idx = rep * 256 + t;
            int k = idx >> 6, ol = idx & 63;
            float s = sm[ol][k];
            float v = ((k & 31) >= 16) ? (s - sm[ol][k - 16]) : s;  // bit-4 diff
            wT[k * O_TOTAL + o0 + ol] = v;            // coalesced write
        }
    }

    const int gid = blockIdx.x * BLOCK + t;           // 48*256 = 12288 exactly
    if (gid < O_TOTAL * NIN) {
        // int64 little-endian with values < 2048 => odd u32 words are all 0.
        bool is64 = ((map_raw[1] | map_raw[3] | map_raw[5] | map_raw[7]) == 0u);
        int val = is64 ? (int)map_raw[2 * gid] : (int)map_raw[gid];
        int oo = gid / NIN, ii = gid - oo * NIN;
        m32T[ii * O_TOTAL + oo] = val;
    }
}

// ---------------------------------------------------------------------------
// Main, v8 — attack the measured symptom (all pipes <25% busy, occupancy 20%,
// T invariant across 5 memory structures => latency-bound, too few waves):
//  * lane-pair k-split: thread h of a pair owns 32 weights (k-half h), holds
//    ww[32]+t[16] instead of ww[64]+tt[32]  ->  VGPR ~150 -> ~95,
//    __launch_bounds__(256,5): 5 waves/SIMD, LDS 32KB -> 5 blocks/CU
//  * grid 2048 blocks (was 1024): 8 blocks/CU available -> residency stays full
//  * per chunk: each thread gathers its OWN row (6 ds_read, same as v2),
//    shfl_xor(1) shares the other row's xv + the partner subtree result
//  * final: res = fma(x5, T1-T0, T0) across the pair (bit-5 combine)
//  * staging/dbuf/global_load_lds verbatim v2 (best measured structure)
// ---------------------------------------------------------------------------
__device__ __forceinline__ void async_cp16(float* lds, const float* g)
{
    __builtin_amdgcn_global_load_lds(
        (const __attribute__((address_space(1))) void*)g,
        (__attribute__((address_space(3))) void*)lds,
        16, 0, 0);
}

// 5-level multilinear subtree over 32 weights (bit4 diff precomputed in ww)
__device__ __forceinline__ float subtree5(const float* __restrict__ ww,
                                          const float xv[5])
{
    float t[16];
    #pragma unroll
    for (int j = 0; j < 16; ++j) t[j] = fmaf(xv[4], ww[j + 16], ww[j]);
    #pragma unroll
    for (int j = 0; j < 8;  ++j) t[j] = fmaf(xv[3], t[j + 8] - t[j], t[j]);
    #pragma unroll
    for (int j = 0; j < 4;  ++j) t[j] = fmaf(xv[2], t[j + 4] - t[j], t[j]);
    #pragma unroll
    for (int j = 0; j < 2;  ++j) t[j] = fmaf(xv[1], t[j + 2] - t[j], t[j]);
    return fmaf(xv[0], t[1] - t[0], t[0]);
}

__global__ __launch_bounds__(BLOCK, 5) void lut_main(
    const float* __restrict__ x,
    const float* __restrict__ wT,
    const int*   __restrict__ m32T,
    float*       __restrict__ out)
{
    __shared__ float xs[2 * CH * I_TOTAL];   // 2 bufs x 2 rows x 8KB = 32 KB

    const int tid  = threadIdx.x;
    const int h    = tid & 1;                // k-half owned by this lane
    const int o    = blockIdx.y * OGROUP + (tid >> 1);
    const int b0   = blockIdx.x * TILE_B;
    const int wave = tid >> 6;
    const int lane = tid & 63;

    // --- issue chunk-0 DMA first; ww/mapping loads hide its latency -------
    {
        const float* src = x + (size_t)b0 * I_TOTAL;
        #pragma unroll
        for (int ti = 0; ti < 4; ++ti) {
            int off = (wave * 4 + ti) * 256;         // wave-uniform float off
            async_cp16(&xs[off], src + off + lane * 4);
        }
    }

    // 32 weights of my half (lo[0:16] + bit4-diff[16:32])
    float ww[32];
    #pragma unroll
    for (int j = 0; j < 32; ++j) ww[j] = wT[(h * 32 + j) * O_TOTAL + o];

    int m[NIN];
    #pragma unroll
    for (int i = 0; i < NIN; ++i) m[i] = m32T[i * O_TOTAL + o];

    __syncthreads();   // drains own vmcnt(0), then barrier

    #pragma unroll 2
    for (int cc = 0; cc < NCHUNK; ++cc) {
        const int buf = cc & 1;

        // issue DMA for next chunk into the other buffer
        if (cc + 1 < NCHUNK) {
            const float* src = x + (size_t)(b0 + (cc + 1) * CH) * I_TOTAL;
            float* dst = &xs[(buf ^ 1) * CH * I_TOTAL];
            #pragma unroll
            for (int ti = 0; ti < 4; ++ti) {
                int off = (wave * 4 + ti) * 256;
                async_cp16(dst + off, src + off + lane * 4);
            }
        }

        // --- gather MY row's 6 x-values (6 ds_read_b32, random banks) -----
        const int rowc0 = (buf * CH) * I_TOTAL;            // compile-time
        const int myrow = rowc0 + h * I_TOTAL;             // lane-select
        float g[NIN];
        #pragma unroll
        for (int i = 0; i < NIN; ++i) g[i] = xs[myrow + m[i]];

        // other row's xv[0..4] via pair exchange (DPP/swizzle, cheap)
        float xo[5];
        #pragma unroll
        for (int i = 0; i < 5; ++i) xo[i] = __shfl_xor(g[i], 1);

        // A = my half, my row;  B = my half, other row
        float A = subtree5(ww, g);
        float B = subtree5(ww, xo);

        // partner's B == partner half evaluated on MY row
        float Tp = __shfl_xor(B, 1);

        float T0 = h ? Tp : A;
        float T1 = h ? A  : Tp;
        float res = fmaf(g[5], T1 - T0, T0);   // bit-5 combine, x5 of my row

        out[(size_t)(b0 + cc * CH + h) * O_TOTAL + o] = res;

        __syncthreads();  // own DMA drained (vmcnt 0) + all waves done with buf
    }
}

extern "C" void kernel_launch(void* const* d_in, const int* in_sizes, int n_in,
                              void* d_out, int out_size, void* d_ws, size_t ws_size,
                              hipStream_t stream)
{
    const float*        x       = (const float*)d_in[0];
    const float*        table   = (const float*)d_in[1];
    const unsigned int* map_raw = (const unsigned int*)d_in[2];
    float* out  = (float*)d_out;
    float* wT   = (float*)d_ws;                                        // 512 KB
    int*   m32T = (int*)((char*)d_ws + (size_t)O_TOTAL * KW * sizeof(float)); // +48 KB

    prep_kernel<<<48, BLOCK, 0, stream>>>(table, map_raw, wT, m32T);

    dim3 grid(BBLOCKS, OBLOCKS);
    lut_main<<<grid, dim3(BLOCK), 0, stream>>>(x, wT, m32T, out);
}

// Round 9
// 88.824 us; speedup vs baseline: 1.0631x; 1.0631x over previous
//
#include <hip/hip_runtime.h>
#include <math.h>

#define B_TOTAL 2048
#define I_TOTAL 2048
#define O_TOTAL 2048
#define KW 64
#define NIN 6
#define BLOCK 256
#define TILE_B 4               // b-rows per block (was 16) -> 4x grid depth
#define CH 2                   // rows per LDS buffer (double-buffered)
#define NCHUNK (TILE_B / CH)   // 2 barrier-gated chunks (was 8)
#define BBLOCKS (B_TOTAL / TILE_B)  /* 512 */
#define OBLOCKS (O_TOTAL / BLOCK)   /* 8   */

// ---------------------------------------------------------------------------
// prep_kernel (verbatim v2 — the best-measured pairing with the main tree):
//  blocks 0..31: table -> wT[k][o] via 64x65 LDS transpose (coalesced)
//     k<32 : sigmoid(table[o][k])                          ("lo")
//     k>=32: sigmoid(table[o][k]) - sigmoid(table[o][k-32]) (bit-5 diff)
//  all 48 blocks: mapping -> transposed int32 m32T[i][o]
// ---------------------------------------------------------------------------
__global__ __launch_bounds__(BLOCK) void prep_kernel(
    const float* __restrict__ table,
    const unsigned int* __restrict__ map_raw,
    float* __restrict__ wT,
    int* __restrict__ m32T)
{
    const int t = threadIdx.x;

    if (blockIdx.x < 32) {
        __shared__ float sm[64][65];          // +1 pad: conflict-free col reads
        const int o0 = blockIdx.x * 64;
        #pragma unroll
        for (int rep = 0; rep < 16; ++rep) {
            int idx = rep * 256 + t;          // 0..4095
            int ol = idx >> 6, k = idx & 63;
            float v = table[(o0 + ol) * KW + k];      // coalesced read
            sm[ol][k] = 1.0f / (1.0f + __expf(-v));
        }
        __syncthreads();
        #pragma unroll
        for (int rep = 0; rep < 16; ++rep) {
            int idx = rep * 256 + t;
            int k = idx >> 6, ol = idx & 63;
            float s = sm[ol][k];
            float v = (k >= 32) ? (s - sm[ol][k - 32]) : s;
            wT[k * O_TOTAL + o0 + ol] = v;            // coalesced write
        }
    }

    const int gid = blockIdx.x * BLOCK + t;           // 48*256 = 12288 exactly
    if (gid < O_TOTAL * NIN) {
        // int64 little-endian with values < 2048 => odd u32 words are all 0.
        bool is64 = ((map_raw[1] | map_raw[3] | map_raw[5] | map_raw[7]) == 0u);
        int val = is64 ? (int)map_raw[2 * gid] : (int)map_raw[gid];
        int oo = gid / NIN, ii = gid - oo * NIN;
        m32T[ii * O_TOTAL + oo] = val;
    }
}

// ---------------------------------------------------------------------------
// Main, v9 = v2 verbatim except TILE_B 16 -> 4 (the untested axis):
//   Evidence: v2/v4/v6 all ~85-89us with 512-1024 blocks (2-4/CU), serial
//   chains of 4-8 barrier-gated chunks, measured pipes all <25% busy and
//   occupancy 20% — latency-bound at shallow dispatch depth after the 256MiB
//   fill flushes L2/L3 (cold ~1000cy restages that tiny per-chunk compute
//   can't overlap; ramp/tail huge on a 4-deep grid).
//   v9: 4096 blocks (16/CU deep), 2 chunks/block, same 32KB LDS (5 blk/CU),
//   same register-resident ww[64], same scalar fma tree (bit-identical).
//   Cost accepted: wT re-read 4x (L2-resident, ~7.5us aggregate, overlapped).
// ---------------------------------------------------------------------------
__device__ __forceinline__ void async_cp16(float* lds, const float* g)
{
    __builtin_amdgcn_global_load_lds(
        (const __attribute__((address_space(1))) void*)g,
        (__attribute__((address_space(3))) void*)lds,
        16, 0, 0);
}

__global__ __launch_bounds__(BLOCK, 3) void lut_main(
    const float* __restrict__ x,
    const float* __restrict__ wT,
    const int*   __restrict__ m32T,
    float*       __restrict__ out)
{
    __shared__ float xs[2 * CH * I_TOTAL];   // 2 bufs x 2 rows x 8KB = 32 KB

    const int o    = blockIdx.y * BLOCK + threadIdx.x;
    const int b0   = blockIdx.x * TILE_B;
    const int wave = threadIdx.x >> 6;
    const int lane = threadIdx.x & 63;

    // 64 weights (lo[0:32] + diff[32:64]) -> registers, coalesced loads
    float ww[KW];
    #pragma unroll
    for (int k = 0; k < KW; ++k) ww[k] = wT[k * O_TOTAL + o];

    int m[NIN];
    #pragma unroll
    for (int i = 0; i < NIN; ++i) m[i] = m32T[i * O_TOTAL + o];

    // --- prologue: stage chunk 0 into buf 0 -------------------------------
    {
        const float* src = x + (size_t)b0 * I_TOTAL;
        #pragma unroll
        for (int ti = 0; ti < 4; ++ti) {
            int off = (wave * 4 + ti) * 256;         // wave-uniform float off
            async_cp16(&xs[off], src + off + lane * 4);
        }
    }
    __syncthreads();   // drains own vmcnt(0), then barrier

    #pragma unroll
    for (int cc = 0; cc < NCHUNK; ++cc) {
        const int buf = cc & 1;

        // issue DMA for next chunk into the other buffer
        if (cc + 1 < NCHUNK) {
            const float* src = x + (size_t)(b0 + (cc + 1) * CH) * I_TOTAL;
            float* dst = &xs[(buf ^ 1) * CH * I_TOTAL];
            #pragma unroll
            for (int ti = 0; ti < 4; ++ti) {
                int off = (wave * 4 + ti) * 256;
                async_cp16(dst + off, src + off + lane * 4);
            }
        }

        #pragma unroll
        for (int cr = 0; cr < CH; ++cr) {
            const int rowc = (buf * CH + cr) * I_TOTAL;   // compile-time
            float xv[NIN];
            #pragma unroll
            for (int i = 0; i < NIN; ++i) xv[i] = xs[rowc + m[i]];  // LDS gather

            // multilinear contraction; level 0 uses precomputed lo/diff
            float tt[32];
            #pragma unroll
            for (int j = 0; j < 32; ++j) tt[j] = fmaf(xv[5], ww[j + 32], ww[j]);
            #pragma unroll
            for (int j = 0; j < 16; ++j) tt[j] = fmaf(xv[4], tt[j + 16] - tt[j], tt[j]);
            #pragma unroll
            for (int j = 0; j < 8;  ++j) tt[j] = fmaf(xv[3], tt[j + 8]  - tt[j], tt[j]);
            #pragma unroll
            for (int j = 0; j < 4;  ++j) tt[j] = fmaf(xv[2], tt[j + 4]  - tt[j], tt[j]);
            #pragma unroll
            for (int j = 0; j < 2;  ++j) tt[j] = fmaf(xv[1], tt[j + 2]  - tt[j], tt[j]);
            float res = fmaf(xv[0], tt[1] - tt[0], tt[0]);

            out[(size_t)(b0 + cc * CH + cr) * O_TOTAL + o] = res;  // coalesced
        }

        __syncthreads();  // own DMA drained (vmcnt 0) + all waves done with buf
    }
}

extern "C" void kernel_launch(void* const* d_in, const int* in_sizes, int n_in,
                              void* d_out, int out_size, void* d_ws, size_t ws_size,
                              hipStream_t stream)
{
    const float*        x       = (const float*)d_in[0];
    const float*        table   = (const float*)d_in[1];
    const unsigned int* map_raw = (const unsigned int*)d_in[2];
    float* out  = (float*)d_out;
    float* wT   = (float*)d_ws;                                        // 512 KB
    int*   m32T = (int*)((char*)d_ws + (size_t)O_TOTAL * KW * sizeof(float)); // +48 KB

    prep_kernel<<<48, BLOCK, 0, stream>>>(table, map_raw, wT, m32T);

    dim3 grid(BBLOCKS, OBLOCKS);
    lut_main<<<grid, dim3(BLOCK), 0, stream>>>(x, wT, m32T, out);
}

// Round 11
// 85.721 us; speedup vs baseline: 1.1016x; 1.0362x over previous
//
#include <hip/hip_runtime.h>
#include <math.h>

#define B_TOTAL 2048
#define I_TOTAL 2048
#define O_TOTAL 2048
#define KW 64
#define NIN 6
#define BLOCK 256
#define TILE_B 16              // b-rows per block
#define CH 2                   // rows per LDS buffer (double-buffered)
#define NCHUNK (TILE_B / CH)   // 8
#define BBLOCKS (B_TOTAL / TILE_B)  /* 128 */
#define OBLOCKS (O_TOTAL / BLOCK)   /* 8   */

// ---------------------------------------------------------------------------
// FINAL (best-measured v2 structure, 84.8us in Round 1; resubmitted after an
// infra-flake on the identical source in Round 10).
// Session summary (rounds 0-10): nine structural variants — naive staging,
// async double-buffer (this one), lane-swapped coalesced gathers, 8x-reuse
// sweep, pair-packed math, XCD-temporal swizzle, full fusion, lane-pair
// k-split, 4x dispatch depth — all land 85-96us. Direct counters (R5) show
// every pipe <25% busy; dur decomposes as ~44.5us unconditional harness
// fill + ~2us prep + launch gaps + ~36-40us main whose wall time is
// invariant to every structural lever. v2 is the measured optimum.
// ---------------------------------------------------------------------------
__global__ __launch_bounds__(BLOCK) void prep_kernel(
    const float* __restrict__ table,
    const unsigned int* __restrict__ map_raw,
    float* __restrict__ wT,
    int* __restrict__ m32T)
{
    const int t = threadIdx.x;

    if (blockIdx.x < 32) {
        __shared__ float sm[64][65];          // +1 pad: conflict-free col reads
        const int o0 = blockIdx.x * 64;
        #pragma unroll
        for (int rep = 0; rep < 16; ++rep) {
            int idx = rep * 256 + t;          // 0..4095
            int ol = idx >> 6, k = idx & 63;
            float v = table[(o0 + ol) * KW + k];      // coalesced read
            sm[ol][k] = 1.0f / (1.0f + __expf(-v));
        }
        __syncthreads();
        #pragma unroll
        for (int rep = 0; rep < 16; ++rep) {
            int idx = rep * 256 + t;
            int k = idx >> 6, ol = idx & 63;
            float s = sm[ol][k];
            float v = (k >= 32) ? (s - sm[ol][k - 32]) : s;
            wT[k * O_TOTAL + o0 + ol] = v;            // coalesced write
        }
    }

    const int gid = blockIdx.x * BLOCK + t;           // 48*256 = 12288 exactly
    if (gid < O_TOTAL * NIN) {
        // int64 little-endian with values < 2048 => odd u32 words are all 0.
        bool is64 = ((map_raw[1] | map_raw[3] | map_raw[5] | map_raw[7]) == 0u);
        int val = is64 ? (int)map_raw[2 * gid] : (int)map_raw[gid];
        int oo = gid / NIN, ii = gid - oo * NIN;
        m32T[ii * O_TOTAL + oo] = val;
    }
}

__device__ __forceinline__ void async_cp16(float* lds, const float* g)
{
    __builtin_amdgcn_global_load_lds(
        (const __attribute__((address_space(1))) void*)g,
        (__attribute__((address_space(3))) void*)lds,
        16, 0, 0);
}

__global__ __launch_bounds__(BLOCK, 3) void lut_main(
    const float* __restrict__ x,
    const float* __restrict__ wT,
    const int*   __restrict__ m32T,
    float*       __restrict__ out)
{
    __shared__ float xs[2 * CH * I_TOTAL];   // 2 bufs x 2 rows x 8KB = 32 KB

    const int o    = blockIdx.y * BLOCK + threadIdx.x;
    const int b0   = blockIdx.x * TILE_B;
    const int wave = threadIdx.x >> 6;
    const int lane = threadIdx.x & 63;

    // 64 weights (lo[0:32] + diff[32:64]) -> registers, coalesced loads
    float ww[KW];
    #pragma unroll
    for (int k = 0; k < KW; ++k) ww[k] = wT[k * O_TOTAL + o];

    int m[NIN];
    #pragma unroll
    for (int i = 0; i < NIN; ++i) m[i] = m32T[i * O_TOTAL + o];

    // --- prologue: stage chunk 0 into buf 0 -------------------------------
    {
        const float* src = x + (size_t)b0 * I_TOTAL;
        #pragma unroll
        for (int ti = 0; ti < 4; ++ti) {
            int off = (wave * 4 + ti) * 256;         // wave-uniform float off
            async_cp16(&xs[off], src + off + lane * 4);
        }
    }
    __syncthreads();   // drains own vmcnt(0), then barrier

    #pragma unroll 2
    for (int c = 0; c < NCHUNK; ++c) {
        const int buf = c & 1;

        // issue DMA for next chunk into the other buffer
        if (c + 1 < NCHUNK) {
            const float* src = x + (size_t)(b0 + (c + 1) * CH) * I_TOTAL;
            float* dst = &xs[(buf ^ 1) * CH * I_TOTAL];
            #pragma unroll
            for (int ti = 0; ti < 4; ++ti) {
                int off = (wave * 4 + ti) * 256;
                async_cp16(dst + off, src + off + lane * 4);
            }
        }

        #pragma unroll
        for (int cr = 0; cr < CH; ++cr) {
            const int rowc = (buf * CH + cr) * I_TOTAL;   // compile-time
            float xv[NIN];
            #pragma unroll
            for (int i = 0; i < NIN; ++i) xv[i] = xs[rowc + m[i]];  // LDS gather

            // multilinear contraction; level 0 uses precomputed lo/diff
            float tt[32];
            #pragma unroll
            for (int j = 0; j < 32; ++j) tt[j] = fmaf(xv[5], ww[j + 32], ww[j]);
            #pragma unroll
            for (int j = 0; j < 16; ++j) tt[j] = fmaf(xv[4], tt[j + 16] - tt[j], tt[j]);
            #pragma unroll
            for (int j = 0; j < 8;  ++j) tt[j] = fmaf(xv[3], tt[j + 8]  - tt[j], tt[j]);
            #pragma unroll
            for (int j = 0; j < 4;  ++j) tt[j] = fmaf(xv[2], tt[j + 4]  - tt[j], tt[j]);
            #pragma unroll
            for (int j = 0; j < 2;  ++j) tt[j] = fmaf(xv[1], tt[j + 2]  - tt[j], tt[j]);
            float res = fmaf(xv[0], tt[1] - tt[0], tt[0]);

            out[(size_t)(b0 + c * CH + cr) * O_TOTAL + o] = res;  // coalesced
        }

        __syncthreads();  // own DMA drained (vmcnt 0) + all waves done with buf
    }
}

extern "C" void kernel_launch(void* const* d_in, const int* in_sizes, int n_in,
                              void* d_out, int out_size, void* d_ws, size_t ws_size,
                              hipStream_t stream)
{
    const float*        x       = (const float*)d_in[0];
    const float*        table   = (const float*)d_in[1];
    const unsigned int* map_raw = (const unsigned int*)d_in[2];
    float* out  = (float*)d_out;
    float* wT   = (float*)d_ws;                                        // 512 KB
    int*   m32T = (int*)((char*)d_ws + (size_t)O_TOTAL * KW * sizeof(float)); // +48 KB

    prep_kernel<<<48, BLOCK, 0, stream>>>(table, map_raw, wT, m32T);

    dim3 grid(BBLOCKS, OBLOCKS);
    lut_main<<<grid, dim3(BLOCK), 0, stream>>>(x, wT, m32T, out);
}